// Round 13
// baseline (188.416 us; speedup 1.0000x reference)
//
#include <hip/hip_runtime.h>

// MultiheadSelfAttention w/ RoPE, causal. B=2 S=2048 D=1024 NH=16 HD=64.
// cvt_all (+ global RoPE table) -> gemm_qkv (m97 staging BK=32, M-TILE=64:
// grid 1536 = 6 blocks/CU; XCD swizzle; swapped-operand Q/K RoPE epilogue)
// -> attn (R8-proven QBLK=64 x 8 waves, TBLK=64; padded epilogue) ->
// gemm_out (N=64 tiles, swapped operands, float4 stores).
//
// Lessons: R1 forced-occupancy spills; R2 per-tile grid tail; R3/R4/R10 attn
// rewrites regress vs R8's 44us; R9 inline-asm cvt_pk regresses; R11 qkv
// BK=64 regresses (fatter iters closed on both kernels). R13: the untried
// GEMM lever is thinner blocks -> more residency (worked for gemm_out in
// R5/R6/R8): qkv M-tile 128->64 doubles blocks/CU 3->6 to overlap the
// m97 barrier stall; per-iter work per block HALVES (opposite of R11).

typedef unsigned short u16;
typedef unsigned int   u32;
typedef unsigned long long u64;
using s16x8 = __attribute__((ext_vector_type(8))) short;  // 8 bf16
using f32x4 = __attribute__((ext_vector_type(4))) float;  // 4 fp32 acc

__device__ __forceinline__ u16 f2bf(float f) {
  union { float f; u32 u; } v; v.f = f;
  return (u16)((v.u + 0x7fffu + ((v.u >> 16) & 1u)) >> 16);  // RNE
}
__device__ __forceinline__ float bf2f(u16 h) {
  union { u32 u; float f; } v; v.u = ((u32)h) << 16;
  return v.f;
}

// async 16B global->LDS (DMA; LDS dest = wave-uniform base + lane*16)
__device__ __forceinline__ void gl2lds(const u16* g, u16* l) {
  __builtin_amdgcn_global_load_lds(
      (const __attribute__((address_space(1))) void*)g,
      (__attribute__((address_space(3))) void*)l, 16, 0, 0);
}

// ---------------------------------------------------------------- cvt (fused)
__global__ __launch_bounds__(256) void cvt_all(
    const float* __restrict__ x,
    const float* __restrict__ wq, const float* __restrict__ wk,
    const float* __restrict__ wv, const float* __restrict__ wo,
    u16* __restrict__ xb, u16* __restrict__ wqb, u16* __restrict__ wkb,
    u16* __restrict__ wvb, u16* __restrict__ wob,
    float* __restrict__ rtab, const int* __restrict__ pos) {
  int bid = blockIdx.x;
  if (bid >= 8192) {
    int idx = (bid - 8192) * 256 + threadIdx.x;   // 0..65535
    int s = idx >> 5, pair = idx & 31;
    float p = (float)pos[s];
    float freq = __expf(-0.28782313662425572f * (float)pair);
    float sn, cs;
    sincosf(p * freq, &sn, &cs);
    *(float2*)(rtab + idx * 2) = make_float2(cs, sn);
    return;
  }
  int e = (bid * 256 + threadIdx.x) * 4;
  const float* src; u16* dst; int off;
  const int XN = 4 << 20;
  if (e < XN) { src = x; dst = xb; off = e; }
  else {
    int t = e - XN; int sel = t >> 20; off = t & ((1 << 20) - 1);
    src = sel == 0 ? wq : sel == 1 ? wk : sel == 2 ? wv : wo;
    dst = sel == 0 ? wqb : sel == 1 ? wkb : sel == 2 ? wvb : wob;
  }
  float4 v = *(const float4*)(src + off);
  ushort4 o;
  o.x = f2bf(v.x); o.y = f2bf(v.y); o.z = f2bf(v.z); o.w = f2bf(v.w);
  *(ushort4*)(dst + off) = o;
}

// ---------------------------------------------------------------- QKV proj
// M-TILE=64: C[64x128] = A[64xK] . W[128xK]^T per block. Grid (8,64,3) =
// 1536 blocks = 6/CU (LDS 12.3KB). 4 waves: wm=(wid>>1)*32, wn=(wid&1)*64,
// acc[2][4]. Staging/iter: A 64x32 = 1 chunk/thread; W 128x32 = 2/thread.
// XCD swizzle (1536%8==0, 192/XCD; bx fastest -> A-panel sharers co-XCD).
// z<2: SWAPPED mfma -> s in l15, d in quad*4+r: RoPE pair thread-local,
// 4 d's pack to one u64. z=2 (V): unswapped, packed-u64 over s.
template <bool TAB>
__global__ __launch_bounds__(256) void gemm_qkv_t(
    const u16* __restrict__ xb,
    const u16* __restrict__ wq, const u16* __restrict__ wk,
    const u16* __restrict__ wv, const int* __restrict__ pos,
    const float* __restrict__ rtab,
    u16* __restrict__ qh, u16* __restrict__ kh, u16* __restrict__ vt) {
  __shared__ __align__(16) u16 As[64 * 32];    // 4KB
  __shared__ __align__(16) u16 Bs[128 * 32];   // 8KB
  __shared__ __align__(16) float tabl[TAB ? 2 : 64 * 32 * 2];
  const int K = 1024;
  int id = blockIdx.x + 8 * blockIdx.y + 512 * blockIdx.z;
  int nid = (id & 7) * 192 + (id >> 3);         // XCD swizzle (1536/8=192)
  int bx = nid & 7, by = (nid >> 3) & 63, z = nid >> 9;
  const u16* W = (z == 0) ? wq : (z == 1) ? wk : wv;
  int bm0 = by * 64, bn0 = bx * 128;
  int tid = threadIdx.x;
  if (!TAB && z < 2) {
    for (int idx = tid; idx < 2048; idx += 256) {
      int rl = idx >> 5, pair = idx & 31;
      int s = (bm0 + rl) & 2047;
      float p = (float)pos[s];
      float freq = __expf(-0.28782313662425572f * (float)pair);
      float sn, cs;
      sincosf(p * freq, &sn, &cs);
      tabl[idx * 2] = cs;
      tabl[idx * 2 + 1] = sn;
    }
  }
  int wid = tid >> 6, lane = tid & 63;
  int quad = lane >> 4, l15 = lane & 15;
  int wm = (wid >> 1) * 32, wn = (wid & 1) * 64;
  // A: 256 chunks, 1/thread; W: 512 chunks, 2/thread.
  int chA = tid;
  int ra = chA >> 2, ca = (chA & 3) * 8;
  int ch0 = wid * 128 + lane, ch1 = ch0 + 64;
  int r0 = ch0 >> 2, c0 = (ch0 & 3) * 8;
  int r1 = ch1 >> 2, c1 = (ch1 & 3) * 8;
  const u16* Ab = xb + (size_t)bm0 * K;
  const u16* Wb = W + (size_t)bn0 * K;
  u16* lA0 = As + wid * 512;                 // 64 chunks/wave
  u16* lB0 = Bs + wid * 1024; u16* lB1 = lB0 + 512;
  f32x4 acc[2][4];
  const f32x4 fz = {0.f, 0.f, 0.f, 0.f};
#pragma unroll
  for (int mi = 0; mi < 2; mi++)
#pragma unroll
    for (int ni = 0; ni < 4; ni++) acc[mi][ni] = fz;
  bool swp = (z < 2);
  for (int k0 = 0; k0 < K; k0 += 32) {
    __syncthreads();
    gl2lds(Ab + (size_t)ra * K + k0 + ca, lA0);
    gl2lds(Wb + (size_t)r0 * K + k0 + c0, lB0);
    gl2lds(Wb + (size_t)r1 * K + k0 + c1, lB1);
    __syncthreads();
    s16x8 af[2], bf[4];
#pragma unroll
    for (int mi = 0; mi < 2; mi++)
      af[mi] = *(const s16x8*)(As + (wm + mi * 16 + l15) * 32 + quad * 8);
#pragma unroll
    for (int ni = 0; ni < 4; ni++)
      bf[ni] = *(const s16x8*)(Bs + (wn + ni * 16 + l15) * 32 + quad * 8);
    if (swp) {
#pragma unroll
      for (int mi = 0; mi < 2; mi++)
#pragma unroll
        for (int ni = 0; ni < 4; ni++)
          acc[mi][ni] = __builtin_amdgcn_mfma_f32_16x16x32_bf16(
              bf[ni], af[mi], acc[mi][ni], 0, 0, 0);
    } else {
#pragma unroll
      for (int mi = 0; mi < 2; mi++)
#pragma unroll
        for (int ni = 0; ni < 4; ni++)
          acc[mi][ni] = __builtin_amdgcn_mfma_f32_16x16x32_bf16(
              af[mi], bf[ni], acc[mi][ni], 0, 0, 0);
    }
  }
  if (z < 2) {
    u16* dst = (z == 0) ? qh : kh;
    float qs = (z == 0) ? 0.125f : 1.0f;
    int h2 = (bn0 + wn) >> 6;               // (bn0+wn) is 64-aligned
#pragma unroll
    for (int mi = 0; mi < 2; mi++) {
      int rowg = bm0 + wm + mi * 16 + l15;  // s in lane dim
      int b2 = rowg >> 11, s2 = rowg & 2047;
      int rl = wm + mi * 16 + l15;          // local row for tabl
#pragma unroll
      for (int ni = 0; ni < 4; ni++) {
        int d0 = ni * 16 + quad * 4;        // 4 consecutive d in regs
        float cs0, sn0, cs1, sn1;
        if (TAB) {
          float2 t0 = *(const float2*)(rtab + (size_t)(s2 * 32 + (d0 >> 1)) * 2);
          float2 t1 = *(const float2*)(rtab + (size_t)(s2 * 32 + (d0 >> 1) + 1) * 2);
          cs0 = t0.x; sn0 = t0.y; cs1 = t1.x; sn1 = t1.y;
        } else {
          cs0 = tabl[(rl * 32 + (d0 >> 1)) * 2];
          sn0 = tabl[(rl * 32 + (d0 >> 1)) * 2 + 1];
          cs1 = tabl[(rl * 32 + (d0 >> 1) + 1) * 2];
          sn1 = tabl[(rl * 32 + (d0 >> 1) + 1) * 2 + 1];
        }
        float v0 = acc[mi][ni][0], v1 = acc[mi][ni][1];
        float v2 = acc[mi][ni][2], v3 = acc[mi][ni][3];
        float o0 = (v0 * cs0 - v1 * sn0) * qs;
        float o1 = (v0 * sn0 + v1 * cs0) * qs;
        float o2 = (v2 * cs1 - v3 * sn1) * qs;
        float o3 = (v2 * sn1 + v3 * cs1) * qs;
        u64 pk = (u64)f2bf(o0) | ((u64)f2bf(o1) << 16) |
                 ((u64)f2bf(o2) << 32) | ((u64)f2bf(o3) << 48);
        *(u64*)(dst + (((size_t)(b2 * 16 + h2)) * 2048 + s2) * 64 + d0) = pk;
      }
    }
  } else {
#pragma unroll
    for (int mi = 0; mi < 2; mi++)
#pragma unroll
      for (int ni = 0; ni < 4; ni++) {
        int row0 = bm0 + wm + mi * 16 + quad * 4;
        int col = bn0 + wn + ni * 16 + l15;
        int b = row0 >> 11, s0 = row0 & 2047, h = col >> 6, d = col & 63;
        u64 pk = (u64)f2bf(acc[mi][ni][0]) |
                 ((u64)f2bf(acc[mi][ni][1]) << 16) |
                 ((u64)f2bf(acc[mi][ni][2]) << 32) |
                 ((u64)f2bf(acc[mi][ni][3]) << 48);
        *(u64*)(vt + (((size_t)(b * 16 + h)) * 64 + d) * 2048 + s0) = pk;
      }
  }
}

// ---------------------------------------------------------------- out proj
// N=64 tiles: C[128x64] = A[128x1024].Wo[64x1024]^T. Grid (16,32) = 512
// blocks = 2/CU. XCD-swizzled. Swapped operands -> 4 consecutive cols in
// regs: 8 coalesced float4 stores.
__global__ __launch_bounds__(256) void gemm_out_n64(
    const u16* __restrict__ ao, const u16* __restrict__ wo,
    float* __restrict__ out) {
  __shared__ __align__(16) u16 As[128 * 32];   // 8KB
  __shared__ __align__(16) u16 Bs[64 * 32];    // 4KB
  const int K = 1024;
  int id = blockIdx.x + 16 * blockIdx.y;
  int nid = (id & 7) * 64 + (id >> 3);         // XCD swizzle (512%8==0)
  int bx = nid & 15, by = nid >> 4;
  int bm0 = by * 128, bn0 = bx * 64;
  int tid = threadIdx.x;
  int wid = tid >> 6, lane = tid & 63, quad = lane >> 4, l15 = lane & 15;
  int wm = wid * 32;
  int ch0 = wid * 128 + lane, ch1 = ch0 + 64;
  int ra0 = ch0 >> 2, ca0 = (ch0 & 3) * 8;
  int ra1 = ch1 >> 2, ca1 = (ch1 & 3) * 8;
  int chB = wid * 64 + lane;
  int rb = chB >> 2, cb = (chB & 3) * 8;
  const u16* Ab = ao + (size_t)bm0 * K;
  const u16* Wb = wo + (size_t)bn0 * K;
  u16* lA0 = As + wid * 1024; u16* lA1 = lA0 + 512;
  u16* lB0 = Bs + wid * 512;
  f32x4 acc[2][4];
  const f32x4 fz = {0.f, 0.f, 0.f, 0.f};
#pragma unroll
  for (int mi = 0; mi < 2; mi++)
#pragma unroll
    for (int ni = 0; ni < 4; ni++) acc[mi][ni] = fz;
  for (int k0 = 0; k0 < K; k0 += 32) {
    __syncthreads();
    gl2lds(Ab + (size_t)ra0 * K + k0 + ca0, lA0);
    gl2lds(Ab + (size_t)ra1 * K + k0 + ca1, lA1);
    gl2lds(Wb + (size_t)rb * K + k0 + cb, lB0);
    __syncthreads();
    s16x8 af[2], bf[4];
#pragma unroll
    for (int mi = 0; mi < 2; mi++)
      af[mi] = *(const s16x8*)(As + (wm + mi * 16 + l15) * 32 + quad * 8);
#pragma unroll
    for (int ni = 0; ni < 4; ni++)
      bf[ni] = *(const s16x8*)(Bs + (ni * 16 + l15) * 32 + quad * 8);
#pragma unroll
    for (int mi = 0; mi < 2; mi++)
#pragma unroll
      for (int ni = 0; ni < 4; ni++)
        acc[mi][ni] = __builtin_amdgcn_mfma_f32_16x16x32_bf16(
            bf[ni], af[mi], acc[mi][ni], 0, 0, 0);  // SWAPPED: m in l15
  }
#pragma unroll
  for (int mi = 0; mi < 2; mi++) {
    int row = bm0 + wm + mi * 16 + l15;            // m in lane dim
#pragma unroll
    for (int ni = 0; ni < 4; ni++) {
      int col0 = bn0 + ni * 16 + quad * 4;         // 4 consecutive cols
      float4 v;
      v.x = acc[mi][ni][0]; v.y = acc[mi][ni][1];
      v.z = acc[mi][ni][2]; v.w = acc[mi][ni][3];
      *(float4*)(out + (size_t)row * 1024 + col0) = v;
    }
  }
}

// ---------------------------------------------------------------- attention
// R8-proven: R0 per-wave pipeline, QBLK=64 via 8 waves (512 thr), TBLK=64.
// Epilogue redo stride 17 f32 (breaks the 32-way stride-64B bank conflict
// in the cross-thalf reduction).
#define KTS 72
#define VTS 72
#define PTS 40
#define OTS 72

__global__ __launch_bounds__(512, 4) void attn_k(
    const u16* __restrict__ qh, const u16* __restrict__ kh,
    const u16* __restrict__ vt, u16* __restrict__ ao) {
  __shared__ __align__(16) u16 kv[64 * KTS + 64 * VTS];  // K tile then V tile
  __shared__ __align__(16) u16 pt[8 * 16 * PTS];         // per-wave P^T + ow
  __shared__ __align__(16) float redl2[256];             // lsum partials
  u16* ks = kv;
  u16* vs = kv + 64 * KTS;
  int bid = blockIdx.x;
  int bh = bid & 31, pi = bid >> 5;        // pi 0..15
  int b = bh >> 4, h = bh & 15;
  int tid = threadIdx.x, wid = tid >> 6, lane = tid & 63;
  int quad = lane >> 4, l15 = lane & 15;
  int qsub = wid & 3, thalf = wid >> 2;
  const u16* qbase = qh + (size_t)bh * 2048 * 64;
  const u16* kbase = kh + (size_t)bh * 2048 * 64;
  const u16* vbase = vt + (size_t)bh * 64 * 2048;
  u16* ptw = pt + wid * 16 * PTS;
  const f32x4 fz = {0.f, 0.f, 0.f, 0.f};
  int srow = tid >> 3, sc = (tid & 7) * 8;  // 512 thr: 1 uint4/thread/array
  int tb = thalf * 32;

#pragma unroll
  for (int phase = 0; phase < 2; phase++) {
    int qt = phase ? (31 - pi) : pi;       // q-tile of 64
    int q0 = qt * 64, q0w = q0 + qsub * 16;
    s16x8 qf0 = *(const s16x8*)(qbase + (size_t)(q0w + l15) * 64 + quad * 8);
    s16x8 qf1 = *(const s16x8*)(qbase + (size_t)(q0w + l15) * 64 + 32 + quad * 8);
    f32x4 acc[4];
#pragma unroll
    for (int md = 0; md < 4; md++) acc[md] = fz;
    float lsum = 0.f;
    int qg = q0w + l15;
    int nt = qt + 1;
    uint4 rk0 = *(const uint4*)(kbase + (size_t)srow * 64 + sc);
    uint4 rv0 = *(const uint4*)(vbase + (size_t)srow * 2048 + sc);
    for (int it = 0; it < nt; it++) {
      __syncthreads();
      *(uint4*)(ks + srow * KTS + sc) = rk0;
      *(uint4*)(vs + srow * VTS + sc) = rv0;
      if (it + 1 < nt) {
        int t1 = (it + 1) << 6;
        rk0 = *(const uint4*)(kbase + (size_t)(t1 + srow) * 64 + sc);
        rv0 = *(const uint4*)(vbase + (size_t)srow * 2048 + t1 + sc);
      }
      __syncthreads();
      int t0 = it << 6;
      bool diag = (it == nt - 1);
#pragma unroll
      for (int mt = 0; mt < 2; mt++) {
        int krow = tb + mt * 16 + l15;
        s16x8 ka0 = *(const s16x8*)(ks + krow * KTS + quad * 8);
        s16x8 ka1 = *(const s16x8*)(ks + krow * KTS + 32 + quad * 8);
        f32x4 st = __builtin_amdgcn_mfma_f32_16x16x32_bf16(ka0, qf0, fz, 0, 0, 0);
        st = __builtin_amdgcn_mfma_f32_16x16x32_bf16(ka1, qf1, st, 0, 0, 0);
        u64 pk = 0;
#pragma unroll
        for (int r = 0; r < 4; r++) {
          float p = __expf(st[r]);
          if (diag) {
            int tg = t0 + tb + mt * 16 + quad * 4 + r;
            if (tg > qg) p = 0.f;
          }
          lsum += p;
          pk |= ((u64)f2bf(p)) << (16 * r);
        }
        *(u64*)(ptw + l15 * PTS + mt * 16 + quad * 4) = pk;
      }
      s16x8 pb = *(const s16x8*)(ptw + l15 * PTS + quad * 8);
#pragma unroll
      for (int md = 0; md < 4; md++) {
        s16x8 va = *(const s16x8*)(vs + (md * 16 + l15) * VTS + tb + quad * 8);
        acc[md] = __builtin_amdgcn_mfma_f32_16x16x32_bf16(va, pb, acc[md], 0, 0, 0);
      }
    }
    lsum += __shfl_xor(lsum, 16, 64);
    lsum += __shfl_xor(lsum, 32, 64);
    __syncthreads();
    float* redo = (float*)kv;              // 256 lanes x 17 f32 = 17408B ok
    if (thalf == 1) {
#pragma unroll
      for (int md = 0; md < 4; md++)
#pragma unroll
        for (int r = 0; r < 4; r++)
          redo[(qsub * 64 + lane) * 17 + md * 4 + r] = acc[md][r];
      redl2[qsub * 64 + lane] = lsum;
    }
    __syncthreads();
    if (thalf == 0) {
#pragma unroll
      for (int md = 0; md < 4; md++)
#pragma unroll
        for (int r = 0; r < 4; r++)
          acc[md][r] += redo[(qsub * 64 + lane) * 17 + md * 4 + r];
      lsum += redl2[qsub * 64 + lane];
      float rl = 1.0f / lsum;
      u16* ow = pt + qsub * 16 * OTS;      // thalf==0 -> wid==qsub: own ptw
#pragma unroll
      for (int md = 0; md < 4; md++) {
        u64 ok = 0;
#pragma unroll
        for (int r = 0; r < 4; r++)
          ok |= ((u64)f2bf(acc[md][r] * rl)) << (16 * r);
        *(u64*)(ow + l15 * OTS + md * 16 + quad * 4) = ok;
      }
      int qq = lane >> 2, dc = lane & 3;
      uint4 o0 = *(uint4*)(ow + qq * OTS + dc * 16);
      uint4 o1 = *(uint4*)(ow + qq * OTS + dc * 16 + 8);
      size_t orow = (size_t)b * 2048 + q0 + qsub * 16 + qq;
      *(uint4*)(ao + orow * 1024 + h * 64 + dc * 16) = o0;
      *(uint4*)(ao + orow * 1024 + h * 64 + dc * 16 + 8) = o1;
    }
  }
}

// ---------------------------------------------------------------- launch
extern "C" void kernel_launch(void* const* d_in, const int* in_sizes, int n_in,
                              void* d_out, int out_size, void* d_ws,
                              size_t ws_size, hipStream_t stream) {
  const float* x  = (const float*)d_in[0];
  const int* pos  = (const int*)d_in[1];
  const float* Wq = (const float*)d_in[2];
  const float* Wk = (const float*)d_in[3];
  const float* Wv = (const float*)d_in[4];
  const float* Wo = (const float*)d_in[5];
  float* out = (float*)d_out;

  char* ws = (char*)d_ws;
  const size_t MB = 1u << 20;
  u16* xb  = (u16*)(ws);             // 8 MB  [4096][1024] bf16
  u16* wqb = (u16*)(ws + 8 * MB);
  u16* wkb = (u16*)(ws + 10 * MB);
  u16* wvb = (u16*)(ws + 12 * MB);
  u16* wob = (u16*)(ws + 14 * MB);
  u16* qhb = (u16*)(ws + 16 * MB);   // [B][NH][S][HD]  (RoPE'd, Q scaled)
  u16* khb = (u16*)(ws + 24 * MB);
  u16* vtb = (u16*)(ws + 32 * MB);   // [B][NH][HD][S]
  float* rtab = (float*)(ws + 40 * MB);  // 512 KB RoPE (cos,sin) table
  u16* ao  = xb;  // xb dead after gemm_qkv

  bool tabok = ws_size >= 41 * MB;   // rtab fits

  cvt_all<<<tabok ? 8448 : 8192, 256, 0, stream>>>(
      x, Wq, Wk, Wv, Wo, xb, wqb, wkb, wvb, wob, rtab, pos);
  if (tabok)
    gemm_qkv_t<true><<<dim3(8, 64, 3), 256, 0, stream>>>(
        xb, wqb, wkb, wvb, pos, rtab, qhb, khb, vtb);
  else
    gemm_qkv_t<false><<<dim3(8, 64, 3), 256, 0, stream>>>(
        xb, wqb, wkb, wvb, pos, rtab, qhb, khb, vtb);
  attn_k<<<512, 512, 0, stream>>>(qhb, khb, vtb, ao);
  gemm_out_n64<<<dim3(16, 32), 256, 0, stream>>>(ao, wob, out);
}

// Round 14
// 176.847 us; speedup vs baseline: 1.0654x; 1.0654x over previous
//
#include <hip/hip_runtime.h>

// MultiheadSelfAttention w/ RoPE, causal. B=2 S=2048 D=1024 NH=16 HD=64.
// FINAL (R8/R12-best restored): cvt_all (+ global RoPE table) -> gemm_qkv
// (m97 staging BK=32, 128x128 tiles; XCD swizzle; swapped-operand Q/K RoPE
// epilogue) -> attn (QBLK=64 x 8 waves, TBLK=64; padded epilogue) ->
// gemm_out (N=64 tiles, swapped operands, float4 stores).
//
// Closed directions (all measured regressions): R1 forced occupancy
// (spills); R2 per-tile attn grid (tail); R3 dbuf / R4 no-LDS / R10
// TBLK=128 attn rewrites (44us is attn's local opt); R9 inline-asm cvt_pk
// (compiler wins); R11 qkv BK=64 (fatter iters); R13 qkv M=64 (thinner
// blocks: MFMA-per-staged-byte halves). Remaining gap to the sum-of-parts
// (~123us kernels vs ~178 total) is harness fill/launch overhead.

typedef unsigned short u16;
typedef unsigned int   u32;
typedef unsigned long long u64;
using s16x8 = __attribute__((ext_vector_type(8))) short;  // 8 bf16
using f32x4 = __attribute__((ext_vector_type(4))) float;  // 4 fp32 acc

__device__ __forceinline__ u16 f2bf(float f) {
  union { float f; u32 u; } v; v.f = f;
  return (u16)((v.u + 0x7fffu + ((v.u >> 16) & 1u)) >> 16);  // RNE
}
__device__ __forceinline__ float bf2f(u16 h) {
  union { u32 u; float f; } v; v.u = ((u32)h) << 16;
  return v.f;
}

// async 16B global->LDS (DMA; LDS dest = wave-uniform base + lane*16)
__device__ __forceinline__ void gl2lds(const u16* g, u16* l) {
  __builtin_amdgcn_global_load_lds(
      (const __attribute__((address_space(1))) void*)g,
      (__attribute__((address_space(3))) void*)l, 16, 0, 0);
}

// ---------------------------------------------------------------- cvt (fused)
__global__ __launch_bounds__(256) void cvt_all(
    const float* __restrict__ x,
    const float* __restrict__ wq, const float* __restrict__ wk,
    const float* __restrict__ wv, const float* __restrict__ wo,
    u16* __restrict__ xb, u16* __restrict__ wqb, u16* __restrict__ wkb,
    u16* __restrict__ wvb, u16* __restrict__ wob,
    float* __restrict__ rtab, const int* __restrict__ pos) {
  int bid = blockIdx.x;
  if (bid >= 8192) {
    int idx = (bid - 8192) * 256 + threadIdx.x;   // 0..65535
    int s = idx >> 5, pair = idx & 31;
    float p = (float)pos[s];
    float freq = __expf(-0.28782313662425572f * (float)pair);
    float sn, cs;
    sincosf(p * freq, &sn, &cs);
    *(float2*)(rtab + idx * 2) = make_float2(cs, sn);
    return;
  }
  int e = (bid * 256 + threadIdx.x) * 4;
  const float* src; u16* dst; int off;
  const int XN = 4 << 20;
  if (e < XN) { src = x; dst = xb; off = e; }
  else {
    int t = e - XN; int sel = t >> 20; off = t & ((1 << 20) - 1);
    src = sel == 0 ? wq : sel == 1 ? wk : sel == 2 ? wv : wo;
    dst = sel == 0 ? wqb : sel == 1 ? wkb : sel == 2 ? wvb : wob;
  }
  float4 v = *(const float4*)(src + off);
  ushort4 o;
  o.x = f2bf(v.x); o.y = f2bf(v.y); o.z = f2bf(v.z); o.w = f2bf(v.w);
  *(ushort4*)(dst + off) = o;
}

// ---------------------------------------------------------------- GEMM core
// m97 structure (R8-proven): C[128x128] = A[128xK] . W[128xK]^T, bf16, BK=32.
// SWAP=true: acc[mi][ni] = W-row in (quad*4+r), A-row in l15 (C^T fragment).
template <bool SWAP>
__device__ __forceinline__ void gemm_core(
    const u16* __restrict__ A, const u16* __restrict__ W,
    u16* As, u16* Bs, int bm0, int bn0, f32x4 (&acc)[4][4]) {
  const int K = 1024;
  int tid = threadIdx.x;
  int wid = tid >> 6, lane = tid & 63, quad = lane >> 4, l15 = lane & 15;
  int wm = (wid >> 1) * 64, wn = (wid & 1) * 64;
  int ch0 = wid * 128 + lane, ch1 = ch0 + 64;
  int r0 = ch0 >> 2, c0 = (ch0 & 3) * 8;
  int r1 = ch1 >> 2, c1 = (ch1 & 3) * 8;
  const u16* Ab = A + (size_t)bm0 * K;
  const u16* Wb = W + (size_t)bn0 * K;
  u16* lA0 = As + wid * 1024; u16* lA1 = lA0 + 512;
  u16* lB0 = Bs + wid * 1024; u16* lB1 = lB0 + 512;
  for (int k0 = 0; k0 < K; k0 += 32) {
    __syncthreads();
    gl2lds(Ab + (size_t)r0 * K + k0 + c0, lA0);
    gl2lds(Ab + (size_t)r1 * K + k0 + c1, lA1);
    gl2lds(Wb + (size_t)r0 * K + k0 + c0, lB0);
    gl2lds(Wb + (size_t)r1 * K + k0 + c1, lB1);
    __syncthreads();
    s16x8 af[4], bf[4];
#pragma unroll
    for (int mi = 0; mi < 4; mi++)
      af[mi] = *(const s16x8*)(As + (wm + mi * 16 + l15) * 32 + quad * 8);
#pragma unroll
    for (int ni = 0; ni < 4; ni++)
      bf[ni] = *(const s16x8*)(Bs + (wn + ni * 16 + l15) * 32 + quad * 8);
#pragma unroll
    for (int mi = 0; mi < 4; mi++)
#pragma unroll
      for (int ni = 0; ni < 4; ni++)
        acc[mi][ni] = SWAP
            ? __builtin_amdgcn_mfma_f32_16x16x32_bf16(bf[ni], af[mi],
                                                      acc[mi][ni], 0, 0, 0)
            : __builtin_amdgcn_mfma_f32_16x16x32_bf16(af[mi], bf[ni],
                                                      acc[mi][ni], 0, 0, 0);
  }
}

// ---------------------------------------------------------------- QKV proj
// XCD-swizzled grid (768%8==0). z<2: SWAPPED core -> fragment has s in l15,
// d in quad*4+r: RoPE pair (d,d^1) thread-local; 4 d's pack to one u64.
// z=2 (V): unswapped, packed-u64 over s.
template <bool TAB>
__global__ __launch_bounds__(256) void gemm_qkv_t(
    const u16* __restrict__ xb,
    const u16* __restrict__ wq, const u16* __restrict__ wk,
    const u16* __restrict__ wv, const int* __restrict__ pos,
    const float* __restrict__ rtab,
    u16* __restrict__ qh, u16* __restrict__ kh, u16* __restrict__ vt) {
  __shared__ __align__(16) u16 As[128 * 32];
  __shared__ __align__(16) u16 Bs[128 * 32];
  __shared__ __align__(16) float tabl[TAB ? 2 : 128 * 32 * 2];
  int id = blockIdx.x + 8 * blockIdx.y + 256 * blockIdx.z;
  int nid = (id & 7) * 96 + (id >> 3);          // XCD swizzle
  int bx = nid & 7, by = (nid >> 3) & 31, z = nid >> 8;
  const u16* W = (z == 0) ? wq : (z == 1) ? wk : wv;
  int bm0 = by * 128, bn0 = bx * 128;
  int tid = threadIdx.x;
  if (!TAB && z < 2) {
    for (int idx = tid; idx < 4096; idx += 256) {
      int rl = idx >> 5, pair = idx & 31;
      int s = (bm0 + rl) & 2047;
      float p = (float)pos[s];
      float freq = __expf(-0.28782313662425572f * (float)pair);
      float sn, cs;
      sincosf(p * freq, &sn, &cs);
      tabl[idx * 2] = cs;
      tabl[idx * 2 + 1] = sn;
    }
  }
  f32x4 acc[4][4];
  const f32x4 fz = {0.f, 0.f, 0.f, 0.f};
#pragma unroll
  for (int mi = 0; mi < 4; mi++)
#pragma unroll
    for (int ni = 0; ni < 4; ni++) acc[mi][ni] = fz;
  int wid = tid >> 6, lane = tid & 63;
  int quad = lane >> 4, l15 = lane & 15;
  int wm = (wid >> 1) * 64, wn = (wid & 1) * 64;
  if (z < 2) {
    gemm_core<true>(xb, W, As, Bs, bm0, bn0, acc);
    u16* dst = (z == 0) ? qh : kh;
    float qs = (z == 0) ? 0.125f : 1.0f;
    int h2 = (bn0 + wn) >> 6;               // (bn0+wn) is 64-aligned
#pragma unroll
    for (int mi = 0; mi < 4; mi++) {
      int rowg = bm0 + wm + mi * 16 + l15;  // s in lane dim
      int b2 = rowg >> 11, s2 = rowg & 2047;
      int rl = wm + mi * 16 + l15;          // local row for tabl
#pragma unroll
      for (int ni = 0; ni < 4; ni++) {
        int d0 = ni * 16 + quad * 4;        // 4 consecutive d in regs
        float cs0, sn0, cs1, sn1;
        if (TAB) {
          float2 t0 = *(const float2*)(rtab + (size_t)(s2 * 32 + (d0 >> 1)) * 2);
          float2 t1 = *(const float2*)(rtab + (size_t)(s2 * 32 + (d0 >> 1) + 1) * 2);
          cs0 = t0.x; sn0 = t0.y; cs1 = t1.x; sn1 = t1.y;
        } else {
          cs0 = tabl[(rl * 32 + (d0 >> 1)) * 2];
          sn0 = tabl[(rl * 32 + (d0 >> 1)) * 2 + 1];
          cs1 = tabl[(rl * 32 + (d0 >> 1) + 1) * 2];
          sn1 = tabl[(rl * 32 + (d0 >> 1) + 1) * 2 + 1];
        }
        float v0 = acc[mi][ni][0], v1 = acc[mi][ni][1];
        float v2 = acc[mi][ni][2], v3 = acc[mi][ni][3];
        float o0 = (v0 * cs0 - v1 * sn0) * qs;
        float o1 = (v0 * sn0 + v1 * cs0) * qs;
        float o2 = (v2 * cs1 - v3 * sn1) * qs;
        float o3 = (v2 * sn1 + v3 * cs1) * qs;
        u64 pk = (u64)f2bf(o0) | ((u64)f2bf(o1) << 16) |
                 ((u64)f2bf(o2) << 32) | ((u64)f2bf(o3) << 48);
        *(u64*)(dst + (((size_t)(b2 * 16 + h2)) * 2048 + s2) * 64 + d0) = pk;
      }
    }
  } else {
    gemm_core<false>(xb, W, As, Bs, bm0, bn0, acc);
#pragma unroll
    for (int mi = 0; mi < 4; mi++)
#pragma unroll
      for (int ni = 0; ni < 4; ni++) {
        int row0 = bm0 + wm + mi * 16 + quad * 4;
        int col = bn0 + wn + ni * 16 + l15;
        int b = row0 >> 11, s0 = row0 & 2047, h = col >> 6, d = col & 63;
        u64 pk = (u64)f2bf(acc[mi][ni][0]) |
                 ((u64)f2bf(acc[mi][ni][1]) << 16) |
                 ((u64)f2bf(acc[mi][ni][2]) << 32) |
                 ((u64)f2bf(acc[mi][ni][3]) << 48);
        *(u64*)(vt + (((size_t)(b * 16 + h)) * 64 + d) * 2048 + s0) = pk;
      }
  }
}

// ---------------------------------------------------------------- out proj
// N=64 tiles: C[128x64] = A[128x1024].Wo[64x1024]^T. Grid (16,32) = 512
// blocks = 2/CU. XCD-swizzled. Swapped operands -> each thread holds 4
// consecutive output cols: 8 coalesced float4 stores.
__global__ __launch_bounds__(256) void gemm_out_n64(
    const u16* __restrict__ ao, const u16* __restrict__ wo,
    float* __restrict__ out) {
  __shared__ __align__(16) u16 As[128 * 32];   // 8KB
  __shared__ __align__(16) u16 Bs[64 * 32];    // 4KB
  const int K = 1024;
  int id = blockIdx.x + 16 * blockIdx.y;
  int nid = (id & 7) * 64 + (id >> 3);         // XCD swizzle (512%8==0)
  int bx = nid & 15, by = nid >> 4;
  int bm0 = by * 128, bn0 = bx * 64;
  int tid = threadIdx.x;
  int wid = tid >> 6, lane = tid & 63, quad = lane >> 4, l15 = lane & 15;
  int wm = wid * 32;
  int ch0 = wid * 128 + lane, ch1 = ch0 + 64;
  int ra0 = ch0 >> 2, ca0 = (ch0 & 3) * 8;
  int ra1 = ch1 >> 2, ca1 = (ch1 & 3) * 8;
  int chB = wid * 64 + lane;
  int rb = chB >> 2, cb = (chB & 3) * 8;
  const u16* Ab = ao + (size_t)bm0 * K;
  const u16* Wb = wo + (size_t)bn0 * K;
  u16* lA0 = As + wid * 1024; u16* lA1 = lA0 + 512;
  u16* lB0 = Bs + wid * 512;
  f32x4 acc[2][4];
  const f32x4 fz = {0.f, 0.f, 0.f, 0.f};
#pragma unroll
  for (int mi = 0; mi < 2; mi++)
#pragma unroll
    for (int ni = 0; ni < 4; ni++) acc[mi][ni] = fz;
  for (int k0 = 0; k0 < K; k0 += 32) {
    __syncthreads();
    gl2lds(Ab + (size_t)ra0 * K + k0 + ca0, lA0);
    gl2lds(Ab + (size_t)ra1 * K + k0 + ca1, lA1);
    gl2lds(Wb + (size_t)rb * K + k0 + cb, lB0);
    __syncthreads();
    s16x8 af[2], bf[4];
#pragma unroll
    for (int mi = 0; mi < 2; mi++)
      af[mi] = *(const s16x8*)(As + (wm + mi * 16 + l15) * 32 + quad * 8);
#pragma unroll
    for (int ni = 0; ni < 4; ni++)
      bf[ni] = *(const s16x8*)(Bs + (ni * 16 + l15) * 32 + quad * 8);
#pragma unroll
    for (int mi = 0; mi < 2; mi++)
#pragma unroll
      for (int ni = 0; ni < 4; ni++)
        acc[mi][ni] = __builtin_amdgcn_mfma_f32_16x16x32_bf16(
            bf[ni], af[mi], acc[mi][ni], 0, 0, 0);  // SWAPPED: m in l15
  }
#pragma unroll
  for (int mi = 0; mi < 2; mi++) {
    int row = bm0 + wm + mi * 16 + l15;            // m in lane dim
#pragma unroll
    for (int ni = 0; ni < 4; ni++) {
      int col0 = bn0 + ni * 16 + quad * 4;         // 4 consecutive cols
      float4 v;
      v.x = acc[mi][ni][0]; v.y = acc[mi][ni][1];
      v.z = acc[mi][ni][2]; v.w = acc[mi][ni][3];
      *(float4*)(out + (size_t)row * 1024 + col0) = v;
    }
  }
}

// ---------------------------------------------------------------- attention
// R8-proven: R0 per-wave pipeline, QBLK=64 via 8 waves (512 thr), TBLK=64.
// Epilogue redo stride 17 f32 (breaks the 32-way stride-64B bank conflict
// in the cross-thalf reduction).
#define KTS 72
#define VTS 72
#define PTS 40
#define OTS 72

__global__ __launch_bounds__(512, 4) void attn_k(
    const u16* __restrict__ qh, const u16* __restrict__ kh,
    const u16* __restrict__ vt, u16* __restrict__ ao) {
  __shared__ __align__(16) u16 kv[64 * KTS + 64 * VTS];  // K tile then V tile
  __shared__ __align__(16) u16 pt[8 * 16 * PTS];         // per-wave P^T + ow
  __shared__ __align__(16) float redl2[256];             // lsum partials
  u16* ks = kv;
  u16* vs = kv + 64 * KTS;
  int bid = blockIdx.x;
  int bh = bid & 31, pi = bid >> 5;        // pi 0..15
  int b = bh >> 4, h = bh & 15;
  int tid = threadIdx.x, wid = tid >> 6, lane = tid & 63;
  int quad = lane >> 4, l15 = lane & 15;
  int qsub = wid & 3, thalf = wid >> 2;
  const u16* qbase = qh + (size_t)bh * 2048 * 64;
  const u16* kbase = kh + (size_t)bh * 2048 * 64;
  const u16* vbase = vt + (size_t)bh * 64 * 2048;
  u16* ptw = pt + wid * 16 * PTS;
  const f32x4 fz = {0.f, 0.f, 0.f, 0.f};
  int srow = tid >> 3, sc = (tid & 7) * 8;  // 512 thr: 1 uint4/thread/array
  int tb = thalf * 32;

#pragma unroll
  for (int phase = 0; phase < 2; phase++) {
    int qt = phase ? (31 - pi) : pi;       // q-tile of 64
    int q0 = qt * 64, q0w = q0 + qsub * 16;
    s16x8 qf0 = *(const s16x8*)(qbase + (size_t)(q0w + l15) * 64 + quad * 8);
    s16x8 qf1 = *(const s16x8*)(qbase + (size_t)(q0w + l15) * 64 + 32 + quad * 8);
    f32x4 acc[4];
#pragma unroll
    for (int md = 0; md < 4; md++) acc[md] = fz;
    float lsum = 0.f;
    int qg = q0w + l15;
    int nt = qt + 1;
    uint4 rk0 = *(const uint4*)(kbase + (size_t)srow * 64 + sc);
    uint4 rv0 = *(const uint4*)(vbase + (size_t)srow * 2048 + sc);
    for (int it = 0; it < nt; it++) {
      __syncthreads();
      *(uint4*)(ks + srow * KTS + sc) = rk0;
      *(uint4*)(vs + srow * VTS + sc) = rv0;
      if (it + 1 < nt) {
        int t1 = (it + 1) << 6;
        rk0 = *(const uint4*)(kbase + (size_t)(t1 + srow) * 64 + sc);
        rv0 = *(const uint4*)(vbase + (size_t)srow * 2048 + t1 + sc);
      }
      __syncthreads();
      int t0 = it << 6;
      bool diag = (it == nt - 1);
#pragma unroll
      for (int mt = 0; mt < 2; mt++) {
        int krow = tb + mt * 16 + l15;
        s16x8 ka0 = *(const s16x8*)(ks + krow * KTS + quad * 8);
        s16x8 ka1 = *(const s16x8*)(ks + krow * KTS + 32 + quad * 8);
        f32x4 st = __builtin_amdgcn_mfma_f32_16x16x32_bf16(ka0, qf0, fz, 0, 0, 0);
        st = __builtin_amdgcn_mfma_f32_16x16x32_bf16(ka1, qf1, st, 0, 0, 0);
        u64 pk = 0;
#pragma unroll
        for (int r = 0; r < 4; r++) {
          float p = __expf(st[r]);
          if (diag) {
            int tg = t0 + tb + mt * 16 + quad * 4 + r;
            if (tg > qg) p = 0.f;
          }
          lsum += p;
          pk |= ((u64)f2bf(p)) << (16 * r);
        }
        *(u64*)(ptw + l15 * PTS + mt * 16 + quad * 4) = pk;
      }
      s16x8 pb = *(const s16x8*)(ptw + l15 * PTS + quad * 8);
#pragma unroll
      for (int md = 0; md < 4; md++) {
        s16x8 va = *(const s16x8*)(vs + (md * 16 + l15) * VTS + tb + quad * 8);
        acc[md] = __builtin_amdgcn_mfma_f32_16x16x32_bf16(va, pb, acc[md], 0, 0, 0);
      }
    }
    lsum += __shfl_xor(lsum, 16, 64);
    lsum += __shfl_xor(lsum, 32, 64);
    __syncthreads();
    float* redo = (float*)kv;              // 256 lanes x 17 f32 = 17408B ok
    if (thalf == 1) {
#pragma unroll
      for (int md = 0; md < 4; md++)
#pragma unroll
        for (int r = 0; r < 4; r++)
          redo[(qsub * 64 + lane) * 17 + md * 4 + r] = acc[md][r];
      redl2[qsub * 64 + lane] = lsum;
    }
    __syncthreads();
    if (thalf == 0) {
#pragma unroll
      for (int md = 0; md < 4; md++)
#pragma unroll
        for (int r = 0; r < 4; r++)
          acc[md][r] += redo[(qsub * 64 + lane) * 17 + md * 4 + r];
      lsum += redl2[qsub * 64 + lane];
      float rl = 1.0f / lsum;
      u16* ow = pt + qsub * 16 * OTS;      // thalf==0 -> wid==qsub: own ptw
#pragma unroll
      for (int md = 0; md < 4; md++) {
        u64 ok = 0;
#pragma unroll
        for (int r = 0; r < 4; r++)
          ok |= ((u64)f2bf(acc[md][r] * rl)) << (16 * r);
        *(u64*)(ow + l15 * OTS + md * 16 + quad * 4) = ok;
      }
      int qq = lane >> 2, dc = lane & 3;
      uint4 o0 = *(uint4*)(ow + qq * OTS + dc * 16);
      uint4 o1 = *(uint4*)(ow + qq * OTS + dc * 16 + 8);
      size_t orow = (size_t)b * 2048 + q0 + qsub * 16 + qq;
      *(uint4*)(ao + orow * 1024 + h * 64 + dc * 16) = o0;
      *(uint4*)(ao + orow * 1024 + h * 64 + dc * 16 + 8) = o1;
    }
  }
}

// ---------------------------------------------------------------- launch
extern "C" void kernel_launch(void* const* d_in, const int* in_sizes, int n_in,
                              void* d_out, int out_size, void* d_ws,
                              size_t ws_size, hipStream_t stream) {
  const float* x  = (const float*)d_in[0];
  const int* pos  = (const int*)d_in[1];
  const float* Wq = (const float*)d_in[2];
  const float* Wk = (const float*)d_in[3];
  const float* Wv = (const float*)d_in[4];
  const float* Wo = (const float*)d_in[5];
  float* out = (float*)d_out;

  char* ws = (char*)d_ws;
  const size_t MB = 1u << 20;
  u16* xb  = (u16*)(ws);             // 8 MB  [4096][1024] bf16
  u16* wqb = (u16*)(ws + 8 * MB);
  u16* wkb = (u16*)(ws + 10 * MB);
  u16* wvb = (u16*)(ws + 12 * MB);
  u16* wob = (u16*)(ws + 14 * MB);
  u16* qhb = (u16*)(ws + 16 * MB);   // [B][NH][S][HD]  (RoPE'd, Q scaled)
  u16* khb = (u16*)(ws + 24 * MB);
  u16* vtb = (u16*)(ws + 32 * MB);   // [B][NH][HD][S]
  float* rtab = (float*)(ws + 40 * MB);  // 512 KB RoPE (cos,sin) table
  u16* ao  = xb;  // xb dead after gemm_qkv

  bool tabok = ws_size >= 41 * MB;   // rtab fits

  cvt_all<<<tabok ? 8448 : 8192, 256, 0, stream>>>(
      x, Wq, Wk, Wv, Wo, xb, wqb, wkb, wvb, wob, rtab, pos);
  if (tabok)
    gemm_qkv_t<true><<<dim3(8, 32, 3), 256, 0, stream>>>(
        xb, wqb, wkb, wvb, pos, rtab, qhb, khb, vtb);
  else
    gemm_qkv_t<false><<<dim3(8, 32, 3), 256, 0, stream>>>(
        xb, wqb, wkb, wvb, pos, rtab, qhb, khb, vtb);
  attn_k<<<512, 512, 0, stream>>>(qhb, khb, vtb, ao);
  gemm_out_n64<<<dim3(16, 32), 256, 0, stream>>>(ao, wob, out);
}